// Round 1
// baseline (405.127 us; speedup 1.0000x reference)
//
#include <hip/hip_runtime.h>

typedef short bf16x8 __attribute__((ext_vector_type(8)));
typedef float f32x4 __attribute__((ext_vector_type(4)));

#define MFMA_16x16x32_BF16(a, b, c) __builtin_amdgcn_mfma_f32_16x16x32_bf16((a), (b), (c), 0, 0, 0)

__device__ __forceinline__ unsigned short f2bf(float f) {
    unsigned u = __builtin_bit_cast(unsigned, f);
    unsigned r = u + 0x7FFFu + ((u >> 16) & 1u);   // round-to-nearest-even
    return (unsigned short)(r >> 16);
}

__device__ __forceinline__ float sigm(float x) {
    // 1/(1+2^(-x*log2e))
    float e = __builtin_amdgcn_exp2f(-1.44269504088896f * x);
    return __builtin_amdgcn_rcpf(1.0f + e);
}

__device__ __forceinline__ float tanh_fast(float x) {
    // 1 - 2/(1+2^(x*2*log2e))
    float e = __builtin_amdgcn_exp2f(2.88539008177793f * x);
    return 1.0f - 2.0f * __builtin_amdgcn_rcpf(1.0f + e);
}

// One wave handles 16 batch sequences.
// Lane l: batch n = l&15 (of its group), q = l>>4.
// Lane owns hidden units j in {4q..4q+3} (lo) and {16+4q..16+4q+3} (hi) of batch n.
// Gates G = A_x*[x;1] + A_hh*h  via 8 M-tiles of 16: tiles (0,1)=i, (2,3)=f, (4,5)=g, (6,7)=o.
__global__ __launch_bounds__(256, 1) void lstm_mfma_kernel(
    const float* __restrict__ x,     // [B,512,3]
    const float* __restrict__ W_ih,  // [128,3]
    const float* __restrict__ W_hh,  // [128,32]
    const float* __restrict__ b_ih,  // [128]
    const float* __restrict__ b_hh,  // [128]
    const float* __restrict__ W_fc,  // [32]
    const float* __restrict__ b_fc,  // [1]
    float* __restrict__ out,         // [B]
    int n_groups)                    // B/16
{
    const int lane  = threadIdx.x & 63;
    const int wid   = threadIdx.x >> 6;
    const int group = blockIdx.x * 4 + wid;
    if (group >= n_groups) return;

    const int n = lane & 15;
    const int q = lane >> 4;

    // ---- Build constant A fragments (weights, bf16) ----
    // elem j <-> k = (j<4) ? 4q+j : 16 + 4q + (j-4)   (two K=16 halves)
    bf16x8 A_hh[8], A_x[8];
#pragma unroll
    for (int t = 0; t < 8; ++t) {
        const int g = 16 * t + n;  // global gate row (A-row = lane&15 within tile)
        bf16x8 a, ax;
#pragma unroll
        for (int j = 0; j < 8; ++j) {
            const int k = (j < 4) ? (4 * q + j) : (16 + 4 * q + (j - 4));
            a[j] = (short)f2bf(W_hh[g * 32 + k]);
            float axv = 0.0f;
            if (q == 0 && j < 4) {
                axv = (j < 3) ? W_ih[g * 3 + j] : (b_ih[g] + b_hh[g]);
            }
            ax[j] = (short)f2bf(axv);
        }
        A_hh[t] = a;
        A_x[t]  = ax;
    }

    const long bn = (long)group * 16 + n;
    const float* xp = x + bn * (512L * 3);

    // state: c and h (f32), B-fragment of h (bf16)
    float c_lo[4] = {0.f, 0.f, 0.f, 0.f}, c_hi[4] = {0.f, 0.f, 0.f, 0.f};
    float h_lo[4] = {0.f, 0.f, 0.f, 0.f}, h_hi[4] = {0.f, 0.f, 0.f, 0.f};
    bf16x8 Bh = {0, 0, 0, 0, 0, 0, 0, 0};

    // prefetch x(t=0)
    float x0 = xp[0], x1 = xp[1], x2 = xp[2];
    const short one_bf = (short)0x3F80;  // bf16(1.0)

    for (int t = 0; t < 512; ++t) {
        // Pack B_x for this step: meaningful only in (q==0, j<4) slots; the rest
        // multiply zero A-columns (finite garbage is fine, so fill with same).
        bf16x8 Bx;
        Bx[0] = (short)f2bf(x0);
        Bx[1] = (short)f2bf(x1);
        Bx[2] = (short)f2bf(x2);
        Bx[3] = one_bf;
        Bx[4] = Bx[0]; Bx[5] = Bx[1]; Bx[6] = Bx[2]; Bx[7] = Bx[3];

        // prefetch next step's x (latency hidden under this step's work)
        const int tn = (t < 511) ? (t + 1) : 511;
        x0 = xp[tn * 3 + 0];
        x1 = xp[tn * 3 + 1];
        x2 = xp[tn * 3 + 2];

        // Gates: G = A_x * [x;1;0..]  +  A_hh * h
        f32x4 acc[8];
#pragma unroll
        for (int tt = 0; tt < 8; ++tt) {
            f32x4 z = {0.f, 0.f, 0.f, 0.f};
            acc[tt] = MFMA_16x16x32_BF16(A_x[tt], Bx, z);
        }
#pragma unroll
        for (int tt = 0; tt < 8; ++tt) {
            acc[tt] = MFMA_16x16x32_BF16(A_hh[tt], Bh, acc[tt]);
        }

        // Elementwise LSTM cell (lane-local). tiles: 0/1=i, 2/3=f, 4/5=g, 6/7=o
#pragma unroll
        for (int r = 0; r < 4; ++r) {
            float i0 = sigm(acc[0][r]);
            float f0 = sigm(acc[2][r]);
            float g0 = tanh_fast(acc[4][r]);
            float o0 = sigm(acc[6][r]);
            c_lo[r] = f0 * c_lo[r] + i0 * g0;
            h_lo[r] = o0 * tanh_fast(c_lo[r]);

            float i1 = sigm(acc[1][r]);
            float f1 = sigm(acc[3][r]);
            float g1 = tanh_fast(acc[5][r]);
            float o1 = sigm(acc[7][r]);
            c_hi[r] = f1 * c_hi[r] + i1 * g1;
            h_hi[r] = o1 * tanh_fast(c_hi[r]);
        }

        // Pack h into next step's B fragment: elem j<4 -> h_lo[j], j>=4 -> h_hi[j-4]
        bf16x8 bh;
        bh[0] = (short)f2bf(h_lo[0]);
        bh[1] = (short)f2bf(h_lo[1]);
        bh[2] = (short)f2bf(h_lo[2]);
        bh[3] = (short)f2bf(h_lo[3]);
        bh[4] = (short)f2bf(h_hi[0]);
        bh[5] = (short)f2bf(h_hi[1]);
        bh[6] = (short)f2bf(h_hi[2]);
        bh[7] = (short)f2bf(h_hi[3]);
        Bh = bh;
    }

    // FC + sigmoid: out[bn] = sigmoid(sum_j W_fc[j]*h[j] + b_fc)
    float part = 0.f;
#pragma unroll
    for (int r = 0; r < 4; ++r) {
        part += W_fc[4 * q + r] * h_lo[r];
        part += W_fc[16 + 4 * q + r] * h_hi[r];
    }
    part += __shfl_xor(part, 16, 64);
    part += __shfl_xor(part, 32, 64);
    if (q == 0) {
        out[bn] = sigm(part + b_fc[0]);
    }
}

extern "C" void kernel_launch(void* const* d_in, const int* in_sizes, int n_in,
                              void* d_out, int out_size, void* d_ws, size_t ws_size,
                              hipStream_t stream) {
    const float* x    = (const float*)d_in[0];
    const float* W_ih = (const float*)d_in[1];
    const float* W_hh = (const float*)d_in[2];
    const float* b_ih = (const float*)d_in[3];
    const float* b_hh = (const float*)d_in[4];
    const float* W_fc = (const float*)d_in[5];
    const float* b_fc = (const float*)d_in[6];
    float* out        = (float*)d_out;

    const int n_groups = out_size / 16;              // 16384/16 = 1024 waves
    const int n_blocks = (n_groups + 3) / 4;         // 4 waves (256 threads) per block

    hipLaunchKernelGGL(lstm_mfma_kernel, dim3(n_blocks), dim3(256), 0, stream,
                       x, W_ih, W_hh, b_ih, b_hh, W_fc, b_fc, out, n_groups);
}